// Round 1
// baseline (1633.253 us; speedup 1.0000x reference)
//
#include <hip/hip_runtime.h>
#include <hip/hip_bf16.h>

// Problem constants (B,L,D,H,DK,DV) = (4,2048,512,8,64,64)
#define BATCH 4
#define SEQ   2048
#define DMODEL 512
#define NHEAD 8
#define HDIM  64

// ---------------------------------------------------------------------------
// Generic fp32 GEMM + bias: C[M,N] = A[M,K] @ W[K,N] + bias[N]
// 64x64 tile, BK=32, 256 threads, 4x4 micro-tile per thread.
// As stored k-major (transposed) for b128 a-fragment reads.
// ---------------------------------------------------------------------------
__global__ __launch_bounds__(256) void gemm_bias_f32(
    const float* __restrict__ A, const float* __restrict__ W,
    const float* __restrict__ bias, float* __restrict__ C,
    int M, int N, int K)
{
    __shared__ float As[32][64];   // [k][m]
    __shared__ float Bs[32][64];   // [k][n]

    const int t  = threadIdx.x;
    const int tx = t & 15;         // 0..15 -> n micro
    const int ty = t >> 4;         // 0..15 -> m micro
    const int bm = blockIdx.y * 64;
    const int bn = blockIdx.x * 64;

    float acc[4][4] = {};

    for (int k0 = 0; k0 < K; k0 += 32) {
        // Load A tile (64 rows x 32 cols), scatter-transpose into As.
        // Load B tile (32 rows x 64 cols) directly.
        #pragma unroll
        for (int i = 0; i < 2; i++) {
            int id = t + i * 256;
            int ar = id >> 3, ac4 = id & 7;   // 8 float4 per A row
            float4 av = *(const float4*)&A[(size_t)(bm + ar) * K + k0 + ac4 * 4];
            As[ac4 * 4 + 0][ar] = av.x;
            As[ac4 * 4 + 1][ar] = av.y;
            As[ac4 * 4 + 2][ar] = av.z;
            As[ac4 * 4 + 3][ar] = av.w;
            int br = id >> 4, bc4 = id & 15;  // 16 float4 per B row
            *(float4*)&Bs[br][bc4 * 4] =
                *(const float4*)&W[(size_t)(k0 + br) * N + bn + bc4 * 4];
        }
        __syncthreads();

        #pragma unroll
        for (int kk = 0; kk < 32; kk++) {
            float4 a = *(const float4*)&As[kk][ty * 4];
            float4 b = *(const float4*)&Bs[kk][tx * 4];
            acc[0][0] += a.x * b.x; acc[0][1] += a.x * b.y; acc[0][2] += a.x * b.z; acc[0][3] += a.x * b.w;
            acc[1][0] += a.y * b.x; acc[1][1] += a.y * b.y; acc[1][2] += a.y * b.z; acc[1][3] += a.y * b.w;
            acc[2][0] += a.z * b.x; acc[2][1] += a.z * b.y; acc[2][2] += a.z * b.z; acc[2][3] += a.z * b.w;
            acc[3][0] += a.w * b.x; acc[3][1] += a.w * b.y; acc[3][2] += a.w * b.z; acc[3][3] += a.w * b.w;
        }
        __syncthreads();
    }

    float4 bv = *(const float4*)&bias[bn + tx * 4];
    #pragma unroll
    for (int i = 0; i < 4; i++) {
        float4 o;
        o.x = acc[i][0] + bv.x;
        o.y = acc[i][1] + bv.y;
        o.z = acc[i][2] + bv.z;
        o.w = acc[i][3] + bv.w;
        *(float4*)&C[(size_t)(bm + ty * 4 + i) * N + bn + tx * 4] = o;
    }
}

// ---------------------------------------------------------------------------
// Flash-style fp32 attention, one (b,h) head slice, 64-row Q tile per block.
// K and V share one LDS buffer (loaded sequentially) to fit 64 KB static LDS.
// All LDS tiles are 64x64 with XOR chunk swizzle: physical float4-chunk
// index = logical_chunk ^ ((row>>2)&15) -> all b128 reads <=2-way aliased.
// Output written to X in [H, L, B, DV] flat order (the torch mis-reshape).
// ---------------------------------------------------------------------------
__global__ __launch_bounds__(256) void attn_f32(
    const float* __restrict__ qb, const float* __restrict__ kb,
    const float* __restrict__ vb, const float* __restrict__ mask,
    float* __restrict__ X)
{
    __shared__ float Qs[64 * 64];
    __shared__ float KVs[64 * 64];
    __shared__ float Ss[64 * 64];

    const int t  = threadIdx.x;
    const int tx = t & 15;     // column micro (4 cols)
    const int ty = t >> 4;     // row micro (4 rows)
    const int bh = blockIdx.x;
    const int b  = bh / NHEAD;
    const int h  = bh % NHEAD;
    const int q0 = blockIdx.y * 64;

    const float* qbase = qb + (size_t)b * SEQ * DMODEL + h * HDIM;
    const float* kbase = kb + (size_t)b * SEQ * DMODEL + h * HDIM;
    const float* vbase = vb + (size_t)b * SEQ * DMODEL + h * HDIM;

    // Load Q tile (64 rows x 64 features)
    #pragma unroll
    for (int i = 0; i < 4; i++) {
        int id = t + i * 256;
        int r = id >> 4, c4 = id & 15;
        float4 val = *(const float4*)&qbase[(size_t)(q0 + r) * DMODEL + c4 * 4];
        int ch = c4 ^ ((r >> 2) & 15);
        *(float4*)&Qs[r * 64 + ch * 4] = val;
    }

    float m_i[4], l_i[4], O[4][4];
    #pragma unroll
    for (int i = 0; i < 4; i++) {
        m_i[i] = -INFINITY;
        l_i[i] = 0.0f;
        #pragma unroll
        for (int j = 0; j < 4; j++) O[i][j] = 0.0f;
    }

    for (int kt = 0; kt < SEQ / 64; kt++) {
        const int k0 = kt * 64;

        // ---- load K tile into KVs ----
        #pragma unroll
        for (int i = 0; i < 4; i++) {
            int id = t + i * 256;
            int r = id >> 4, c4 = id & 15;
            float4 val = *(const float4*)&kbase[(size_t)(k0 + r) * DMODEL + c4 * 4];
            int ch = c4 ^ ((r >> 2) & 15);
            *(float4*)&KVs[r * 64 + ch * 4] = val;
        }
        __syncthreads();   // (A) K (and Q on first iter) visible

        // ---- S = Q K^T over 64 features ----
        float acc[4][4] = {};
        #pragma unroll
        for (int k4 = 0; k4 < 16; k4++) {
            float4 qv[4], kv[4];
            #pragma unroll
            for (int i = 0; i < 4; i++)
                qv[i] = *(const float4*)&Qs[(ty * 4 + i) * 64 + ((k4 ^ ty) << 2)];
            #pragma unroll
            for (int j = 0; j < 4; j++)
                kv[j] = *(const float4*)&KVs[(tx * 4 + j) * 64 + ((k4 ^ tx) << 2)];
            #pragma unroll
            for (int i = 0; i < 4; i++) {
                acc[i][0] += qv[i].x * kv[0].x + qv[i].y * kv[0].y + qv[i].z * kv[0].z + qv[i].w * kv[0].w;
                acc[i][1] += qv[i].x * kv[1].x + qv[i].y * kv[1].y + qv[i].z * kv[1].z + qv[i].w * kv[1].w;
                acc[i][2] += qv[i].x * kv[2].x + qv[i].y * kv[2].y + qv[i].z * kv[2].z + qv[i].w * kv[2].w;
                acc[i][3] += qv[i].x * kv[3].x + qv[i].y * kv[3].y + qv[i].z * kv[3].z + qv[i].w * kv[3].w;
            }
        }

        // ---- scale + mask, online softmax update ----
        float p[4][4];
        #pragma unroll
        for (int i = 0; i < 4; i++) {
            const int qg = q0 + ty * 4 + i;
            float4 mv = *(const float4*)&mask[(size_t)qg * SEQ + k0 + tx * 4];
            float s0 = acc[i][0] * 0.125f + mv.x;
            float s1 = acc[i][1] * 0.125f + mv.y;
            float s2 = acc[i][2] * 0.125f + mv.z;
            float s3 = acc[i][3] * 0.125f + mv.w;

            float tmax = fmaxf(fmaxf(s0, s1), fmaxf(s2, s3));
            #pragma unroll
            for (int s = 1; s < 16; s <<= 1)
                tmax = fmaxf(tmax, __shfl_xor(tmax, s, 64));

            float mnew  = fmaxf(m_i[i], tmax);
            float alpha = __expf(m_i[i] - mnew);
            float p0 = __expf(s0 - mnew);
            float p1 = __expf(s1 - mnew);
            float p2 = __expf(s2 - mnew);
            float p3 = __expf(s3 - mnew);
            float tsum = p0 + p1 + p2 + p3;
            #pragma unroll
            for (int s = 1; s < 16; s <<= 1)
                tsum += __shfl_xor(tsum, s, 64);

            l_i[i] = l_i[i] * alpha + tsum;
            m_i[i] = mnew;
            #pragma unroll
            for (int j = 0; j < 4; j++) O[i][j] *= alpha;
            p[i][0] = p0; p[i][1] = p1; p[i][2] = p2; p[i][3] = p3;
        }
        __syncthreads();   // (B) all K reads done; prev-tile Ss reads long done

        // ---- load V into KVs (overwrites K), write P into Ss ----
        #pragma unroll
        for (int i = 0; i < 4; i++) {
            int id = t + i * 256;
            int r = id >> 4, c4 = id & 15;
            float4 val = *(const float4*)&vbase[(size_t)(k0 + r) * DMODEL + c4 * 4];
            int ch = c4 ^ ((r >> 2) & 15);
            *(float4*)&KVs[r * 64 + ch * 4] = val;
        }
        #pragma unroll
        for (int i = 0; i < 4; i++) {
            float4 pv4 = make_float4(p[i][0], p[i][1], p[i][2], p[i][3]);
            *(float4*)&Ss[(ty * 4 + i) * 64 + ((tx ^ ty) << 2)] = pv4;
        }
        __syncthreads();   // (C) V and P visible

        // ---- O += P @ V ----
        #pragma unroll
        for (int c4 = 0; c4 < 16; c4++) {
            float4 pv[4], vv[4];
            #pragma unroll
            for (int i = 0; i < 4; i++)
                pv[i] = *(const float4*)&Ss[(ty * 4 + i) * 64 + ((c4 ^ ty) << 2)];
            #pragma unroll
            for (int jj = 0; jj < 4; jj++)
                vv[jj] = *(const float4*)&KVs[(c4 * 4 + jj) * 64 + ((tx ^ c4) << 2)];
            #pragma unroll
            for (int i = 0; i < 4; i++) {
                O[i][0] += pv[i].x * vv[0].x + pv[i].y * vv[1].x + pv[i].z * vv[2].x + pv[i].w * vv[3].x;
                O[i][1] += pv[i].x * vv[0].y + pv[i].y * vv[1].y + pv[i].z * vv[2].y + pv[i].w * vv[3].y;
                O[i][2] += pv[i].x * vv[0].z + pv[i].y * vv[1].z + pv[i].z * vv[2].z + pv[i].w * vv[3].z;
                O[i][3] += pv[i].x * vv[0].w + pv[i].y * vv[1].w + pv[i].z * vv[2].w + pv[i].w * vv[3].w;
            }
        }
        __syncthreads();   // (D) PV done -> next K load / P write safe
    }

    // ---- finalize: divide by l, write X in [H, L, B, DV] flat order ----
    #pragma unroll
    for (int i = 0; i < 4; i++) {
        float inv = 1.0f / l_i[i];
        const int qg = q0 + ty * 4 + i;
        float4 o;
        o.x = O[i][0] * inv;
        o.y = O[i][1] * inv;
        o.z = O[i][2] * inv;
        o.w = O[i][3] * inv;
        size_t idx = (((size_t)h * SEQ + qg) * BATCH + b) * HDIM + tx * 4;
        *(float4*)&X[idx] = o;
    }
}

// ---------------------------------------------------------------------------
extern "C" void kernel_launch(void* const* d_in, const int* in_sizes, int n_in,
                              void* d_out, int out_size, void* d_ws, size_t ws_size,
                              hipStream_t stream) {
    const float* query = (const float*)d_in[0];
    const float* key_  = (const float*)d_in[1];
    const float* value = (const float*)d_in[2];
    const float* mask  = (const float*)d_in[3];
    const float* Wq = (const float*)d_in[4];
    const float* bq = (const float*)d_in[5];
    const float* Wk = (const float*)d_in[6];
    const float* bk = (const float*)d_in[7];
    const float* Wv = (const float*)d_in[8];
    const float* bv = (const float*)d_in[9];
    const float* Wo = (const float*)d_in[10];
    const float* bo = (const float*)d_in[11];
    float* out = (float*)d_out;

    const int M = BATCH * SEQ;           // 8192
    const size_t np = (size_t)M * DMODEL; // 4194304 floats per buffer
    float* qb = (float*)d_ws;
    float* kb = qb + np;
    float* vb = kb + np;
    float* xb = vb + np;

    dim3 gg(DMODEL / 64, M / 64);        // (8, 128)
    gemm_bias_f32<<<gg, 256, 0, stream>>>(query, Wq, bq, qb, M, DMODEL, DMODEL);
    gemm_bias_f32<<<gg, 256, 0, stream>>>(key_,  Wk, bk, kb, M, DMODEL, DMODEL);
    gemm_bias_f32<<<gg, 256, 0, stream>>>(value, Wv, bv, vb, M, DMODEL, DMODEL);

    dim3 ga(BATCH * NHEAD, SEQ / 64);    // (32, 32)
    attn_f32<<<ga, 256, 0, stream>>>(qb, kb, vb, mask, xb);

    gemm_bias_f32<<<gg, 256, 0, stream>>>(xb, Wo, bo, out, M, DMODEL, DMODEL);
}

// Round 2
// 306.476 us; speedup vs baseline: 5.3291x; 5.3291x over previous
//
#include <hip/hip_runtime.h>

#define SEQ    2048
#define DMODEL 512
#define NHEAD  8
#define HDIM   64
#define BATCH  4

typedef short s16x8 __attribute__((ext_vector_type(8)));
typedef float f32x4 __attribute__((ext_vector_type(4)));

// fp32 -> bf16 with round-to-nearest-even (no header dependency)
static __device__ inline unsigned short f2bf(float x) {
    unsigned int u = __builtin_bit_cast(unsigned int, x);
    u += 0x7fffu + ((u >> 16) & 1u);
    return (unsigned short)(u >> 16);
}

// async 16B/lane global->LDS copy (lds base must be wave-uniform)
static __device__ inline void async_cp16(const void* g, void* l) {
    __builtin_amdgcn_global_load_lds(
        (const __attribute__((address_space(1))) unsigned int*)g,
        (__attribute__((address_space(3))) unsigned int*)l,
        16, 0, 0);
}

// ---------------------------------------------------------------------------
// Elementwise cast fp32 -> bf16 (4 elements/thread)
// ---------------------------------------------------------------------------
__global__ __launch_bounds__(256) void cast_bf16(
    const float* __restrict__ in, unsigned short* __restrict__ out, int n4)
{
    int i = blockIdx.x * 256 + threadIdx.x;
    if (i < n4) {
        float4 v = ((const float4*)in)[i];
        ushort4 o;
        o.x = f2bf(v.x); o.y = f2bf(v.y); o.z = f2bf(v.z); o.w = f2bf(v.w);
        ((ushort4*)out)[i] = o;
    }
}

// ---------------------------------------------------------------------------
// Transpose-cast the four 512x512 weight matrices: W[k][n] -> Wt[n][k] bf16
// grid (16,16,4), block 256.
// ---------------------------------------------------------------------------
__global__ __launch_bounds__(256) void transpose_cast_w(
    const float* __restrict__ s0, const float* __restrict__ s1,
    const float* __restrict__ s2, const float* __restrict__ s3,
    unsigned short* __restrict__ d0, unsigned short* __restrict__ d1,
    unsigned short* __restrict__ d2, unsigned short* __restrict__ d3)
{
    const float* S; unsigned short* D;
    switch (blockIdx.z) {
        case 0: S = s0; D = d0; break;
        case 1: S = s1; D = d1; break;
        case 2: S = s2; D = d2; break;
        default: S = s3; D = d3; break;
    }
    __shared__ float T[32][33];
    const int t = threadIdx.x;
    const int r = t >> 3, c = (t & 7) * 4;
    const int k0 = blockIdx.x * 32, n0 = blockIdx.y * 32;
    float4 v = *(const float4*)&S[(size_t)(k0 + r) * DMODEL + n0 + c];
    T[r][c] = v.x; T[r][c + 1] = v.y; T[r][c + 2] = v.z; T[r][c + 3] = v.w;
    __syncthreads();
    ushort4 o;
    o.x = f2bf(T[c + 0][r]); o.y = f2bf(T[c + 1][r]);
    o.z = f2bf(T[c + 2][r]); o.w = f2bf(T[c + 3][r]);
    *(ushort4*)&D[(size_t)(n0 + r) * DMODEL + k0 + c] = o;
}

// ---------------------------------------------------------------------------
// Per-head transpose of the V projection: vb[b*SEQ+key][h*64+dv] ->
// vT[((b*8+h)*64+dv)*SEQ + key].  No LDS: gather 8 keys, write 16B chunk.
// grid (SEQ/64, B*H), block 256.
// ---------------------------------------------------------------------------
__global__ __launch_bounds__(256) void transpose_v(
    const unsigned short* __restrict__ vb, unsigned short* __restrict__ vT)
{
    const int t = threadIdx.x;
    const int key0 = blockIdx.x * 64;
    const int bh = blockIdx.y, b = bh >> 3, h = bh & 7;
    #pragma unroll
    for (int p = 0; p < 2; p++) {
        int cid = p * 256 + t;
        int dv = cid >> 3, kch = cid & 7;
        unsigned int w0 = 0, w1 = 0, w2 = 0, w3 = 0;
        unsigned short tmp[8];
        #pragma unroll
        for (int j = 0; j < 8; j++)
            tmp[j] = vb[(size_t)(b * SEQ + key0 + kch * 8 + j) * DMODEL + h * HDIM + dv];
        w0 = tmp[0] | ((unsigned)tmp[1] << 16);
        w1 = tmp[2] | ((unsigned)tmp[3] << 16);
        w2 = tmp[4] | ((unsigned)tmp[5] << 16);
        w3 = tmp[6] | ((unsigned)tmp[7] << 16);
        uint4 o = make_uint4(w0, w1, w2, w3);
        *(uint4*)&vT[(size_t)((b * NHEAD + h) * HDIM + dv) * SEQ + key0 + kch * 8] = o;
    }
}

// ---------------------------------------------------------------------------
// bf16 MFMA GEMM: C[8192][512] = A[8192][512] @ Bt[512][512]^T + bias
// (Bt is [n][k], k contiguous).  128x64 block tile, BK=32, 256 thr = 4 waves,
// each wave 64m x 32n = 4x2 MFMA tiles of 16x16x32.  m97-style staging.
// ---------------------------------------------------------------------------
template <int WRITE_BF16>
__global__ __launch_bounds__(256) void gemm_mfma(
    const unsigned short* __restrict__ A, const unsigned short* __restrict__ Bt,
    const float* __restrict__ bias, void* __restrict__ Cout)
{
    __shared__ __align__(16) unsigned short As[128 * 32];
    __shared__ __align__(16) unsigned short Bs[64 * 32];

    const int t = threadIdx.x;
    const int lane = t & 63, w = t >> 6;
    const int wm = w >> 1, wn = w & 1;
    const int c = lane & 15, quad = lane >> 4;
    const int bm = blockIdx.y * 128, bn = blockIdx.x * 64;

    f32x4 acc[4][2] = {};

    for (int k0 = 0; k0 < DMODEL; k0 += 32) {
        // A: wave w stages rows [32w, 32w+32) in two 1KB wave-instructions
        #pragma unroll
        for (int i = 0; i < 2; i++) {
            int row = 32 * w + 16 * i + (lane >> 2);
            const unsigned short* gp = A + (size_t)(bm + row) * DMODEL + k0 + (lane & 3) * 8;
            async_cp16(gp, &As[w * 1024 + i * 512]);
        }
        // B: wave w stages rows [16w, 16w+16) in one wave-instruction
        {
            int row = 16 * w + (lane >> 2);
            const unsigned short* gp = Bt + (size_t)(bn + row) * DMODEL + k0 + (lane & 3) * 8;
            async_cp16(gp, &Bs[w * 512]);
        }
        __syncthreads();

        s16x8 af[4], bf[2];
        #pragma unroll
        for (int mt = 0; mt < 4; mt++)
            af[mt] = *(const s16x8*)&As[(wm * 64 + mt * 16 + c) * 32 + quad * 8];
        #pragma unroll
        for (int nt = 0; nt < 2; nt++)
            bf[nt] = *(const s16x8*)&Bs[(wn * 32 + nt * 16 + c) * 32 + quad * 8];
        #pragma unroll
        for (int mt = 0; mt < 4; mt++)
            #pragma unroll
            for (int nt = 0; nt < 2; nt++)
                acc[mt][nt] = __builtin_amdgcn_mfma_f32_16x16x32_bf16(
                    af[mt], bf[nt], acc[mt][nt], 0, 0, 0);
        __syncthreads();
    }

    #pragma unroll
    for (int nt = 0; nt < 2; nt++) {
        int ng = bn + wn * 32 + nt * 16 + c;
        float bv = bias[ng];
        #pragma unroll
        for (int mt = 0; mt < 4; mt++) {
            #pragma unroll
            for (int r = 0; r < 4; r++) {
                int mg = bm + wm * 64 + mt * 16 + quad * 4 + r;
                float v = acc[mt][nt][r] + bv;
                if (WRITE_BF16)
                    ((unsigned short*)Cout)[(size_t)mg * DMODEL + ng] = f2bf(v);
                else
                    ((float*)Cout)[(size_t)mg * DMODEL + ng] = v;
            }
        }
    }
}

// ---------------------------------------------------------------------------
// Flash attention, bf16 MFMA.  One block = one (b,h) and 64 q rows; 4 waves,
// wave w owns q-strip [16w,16w+16).  LDS tiles XOR-chunk swizzled:
// phys_chunk = (feat>>3) ^ (row&7), element at row*64 + phys_chunk*8 + feat&7.
// Output written bf16 to X in the reference's scrambled ((h*L+q)*B+b)*64+dv.
// ---------------------------------------------------------------------------
__global__ __launch_bounds__(256) void attn_mfma(
    const unsigned short* __restrict__ qb, const unsigned short* __restrict__ kb,
    const unsigned short* __restrict__ vT, const float* __restrict__ mask,
    unsigned short* __restrict__ X)
{
    __shared__ __align__(16) unsigned short Qs[64 * 64];
    __shared__ __align__(16) unsigned short Ks[64 * 64];
    __shared__ __align__(16) unsigned short Vs[64 * 64];
    __shared__ __align__(16) unsigned short Ps[64 * 64];

    const int t = threadIdx.x;
    const int lane = t & 63, w = t >> 6;
    const int c = lane & 15, quad = lane >> 4;
    const int bh = blockIdx.x, b = bh >> 3, h = bh & 7;
    const int q0 = blockIdx.y * 64;

    const size_t qoff  = (size_t)(b * SEQ + q0) * DMODEL + h * HDIM;
    const size_t koff0 = (size_t)(b * SEQ) * DMODEL + h * HDIM;
    const size_t voff0 = (size_t)((b * NHEAD + h) * HDIM) * SEQ;

    // Q tile (once)
    #pragma unroll
    for (int p = 0; p < 2; p++) {
        int cid = p * 256 + t;
        int row = cid >> 3, ch = cid & 7;
        uint4 v = *(const uint4*)&qb[qoff + (size_t)row * DMODEL + ch * 8];
        *(uint4*)&Qs[row * 64 + (ch ^ (row & 7)) * 8] = v;
    }

    f32x4 Oacc[4] = {};
    float m_i[4], l_i[4];
    #pragma unroll
    for (int r = 0; r < 4; r++) { m_i[r] = -INFINITY; l_i[r] = 0.f; }

    for (int k0 = 0; k0 < SEQ; k0 += 64) {
        // stage K and V^T tiles (register staging, swizzled)
        #pragma unroll
        for (int p = 0; p < 2; p++) {
            int cid = p * 256 + t;
            int row = cid >> 3, ch = cid & 7;
            int pc = ch ^ (row & 7);
            uint4 kv = *(const uint4*)&kb[koff0 + (size_t)(k0 + row) * DMODEL + ch * 8];
            uint4 vv = *(const uint4*)&vT[voff0 + (size_t)row * SEQ + k0 + ch * 8];
            *(uint4*)&Ks[row * 64 + pc * 8] = kv;
            *(uint4*)&Vs[row * 64 + pc * 8] = vv;
        }
        __syncthreads();

        // ---- S = Q K^T on this wave's strip: 4 col tiles x 2 k-steps ----
        f32x4 S[4] = {};
        #pragma unroll
        for (int s = 0; s < 2; s++) {
            int qrow = w * 16 + c;
            s16x8 a = *(const s16x8*)&Qs[qrow * 64 + (((s * 4 + quad) ^ (qrow & 7))) * 8];
            #pragma unroll
            for (int j = 0; j < 4; j++) {
                int krow = j * 16 + c;
                s16x8 bf = *(const s16x8*)&Ks[krow * 64 + (((s * 4 + quad) ^ (krow & 7))) * 8];
                S[j] = __builtin_amdgcn_mfma_f32_16x16x32_bf16(a, bf, S[j], 0, 0, 0);
            }
        }

        // ---- fp32 softmax (online), rows = quad*4 + r within strip ----
        float pbuf[4][4];
        #pragma unroll
        for (int r = 0; r < 4; r++) {
            int qg = q0 + w * 16 + quad * 4 + r;
            float sc[4];
            #pragma unroll
            for (int j = 0; j < 4; j++)
                sc[j] = S[j][r] * 0.125f + mask[(size_t)qg * SEQ + k0 + j * 16 + c];
            float mx = fmaxf(fmaxf(sc[0], sc[1]), fmaxf(sc[2], sc[3]));
            #pragma unroll
            for (int sft = 1; sft < 16; sft <<= 1)
                mx = fmaxf(mx, __shfl_xor(mx, sft, 64));
            float mnew  = fmaxf(m_i[r], mx);
            float alpha = __expf(m_i[r] - mnew);
            float sum = 0.f;
            #pragma unroll
            for (int j = 0; j < 4; j++) { pbuf[r][j] = __expf(sc[j] - mnew); sum += pbuf[r][j]; }
            #pragma unroll
            for (int sft = 1; sft < 16; sft <<= 1)
                sum += __shfl_xor(sum, sft, 64);
            l_i[r] = l_i[r] * alpha + sum;
            m_i[r] = mnew;
            #pragma unroll
            for (int j = 0; j < 4; j++) Oacc[j][r] *= alpha;
        }

        // ---- P -> LDS (own strip only: no barrier needed before PV) ----
        #pragma unroll
        for (int r = 0; r < 4; r++) {
            int qrow = w * 16 + quad * 4 + r;
            #pragma unroll
            for (int j = 0; j < 4; j++) {
                int key = j * 16 + c;
                Ps[qrow * 64 + ((key >> 3) ^ (qrow & 7)) * 8 + (key & 7)] = f2bf(pbuf[r][j]);
            }
        }

        // ---- O += P @ V ----
        #pragma unroll
        for (int s = 0; s < 2; s++) {
            int qrow = w * 16 + c;
            s16x8 a = *(const s16x8*)&Ps[qrow * 64 + (((s * 4 + quad) ^ (qrow & 7))) * 8];
            #pragma unroll
            for (int j = 0; j < 4; j++) {
                int vrow = j * 16 + c;
                s16x8 bf = *(const s16x8*)&Vs[vrow * 64 + (((s * 4 + quad) ^ (vrow & 7))) * 8];
                Oacc[j] = __builtin_amdgcn_mfma_f32_16x16x32_bf16(a, bf, Oacc[j], 0, 0, 0);
            }
        }
        __syncthreads();   // K/V/P reads done before next stage overwrites
    }

    // ---- epilogue: 1/l scale, bf16 store in scrambled layout ----
    #pragma unroll
    for (int r = 0; r < 4; r++) {
        float inv = 1.0f / l_i[r];
        int qg = q0 + w * 16 + quad * 4 + r;
        #pragma unroll
        for (int j = 0; j < 4; j++) {
            int dv = j * 16 + c;
            X[(((size_t)h * SEQ + qg) * BATCH + b) * HDIM + dv] = f2bf(Oacc[j][r] * inv);
        }
    }
}

// ---------------------------------------------------------------------------
extern "C" void kernel_launch(void* const* d_in, const int* in_sizes, int n_in,
                              void* d_out, int out_size, void* d_ws, size_t ws_size,
                              hipStream_t stream) {
    const float* query = (const float*)d_in[0];
    const float* key_  = (const float*)d_in[1];
    const float* value = (const float*)d_in[2];
    const float* mask  = (const float*)d_in[3];
    const float* Wq = (const float*)d_in[4];
    const float* bq = (const float*)d_in[5];
    const float* Wk = (const float*)d_in[6];
    const float* bk = (const float*)d_in[7];
    const float* Wv = (const float*)d_in[8];
    const float* bv = (const float*)d_in[9];
    const float* Wo = (const float*)d_in[10];
    const float* bo = (const float*)d_in[11];
    float* out = (float*)d_out;

    const size_t NP = (size_t)BATCH * SEQ * DMODEL;   // 4194304 elements
    unsigned short* ws   = (unsigned short*)d_ws;
    unsigned short* in16 = ws;
    unsigned short* qb16 = in16 + NP;
    unsigned short* kb16 = qb16 + NP;
    unsigned short* vb16 = kb16 + NP;
    unsigned short* vT16 = vb16 + NP;
    unsigned short* xb16 = vT16 + NP;
    unsigned short* WqT  = xb16 + NP;
    unsigned short* WkT  = WqT + DMODEL * DMODEL;
    unsigned short* WvT  = WkT + DMODEL * DMODEL;
    unsigned short* WoT  = WvT + DMODEL * DMODEL;
    // total ws use: 6*8MB + 4*0.5MB = 50 MB

    transpose_cast_w<<<dim3(16, 16, 4), 256, 0, stream>>>(
        Wq, Wk, Wv, Wo, WqT, WkT, WvT, WoT);

    const int n4 = (int)(NP / 4);
    dim3 gg(DMODEL / 64, BATCH * SEQ / 128);   // (8, 64)

    cast_bf16<<<dim3(n4 / 256), 256, 0, stream>>>(query, in16, n4);
    gemm_mfma<1><<<gg, 256, 0, stream>>>(in16, WqT, bq, qb16);
    cast_bf16<<<dim3(n4 / 256), 256, 0, stream>>>(key_, in16, n4);
    gemm_mfma<1><<<gg, 256, 0, stream>>>(in16, WkT, bk, kb16);
    cast_bf16<<<dim3(n4 / 256), 256, 0, stream>>>(value, in16, n4);
    gemm_mfma<1><<<gg, 256, 0, stream>>>(in16, WvT, bv, vb16);

    transpose_v<<<dim3(SEQ / 64, BATCH * NHEAD), 256, 0, stream>>>(vb16, vT16);

    attn_mfma<<<dim3(BATCH * NHEAD, SEQ / 64), 256, 0, stream>>>(
        qb16, kb16, vT16, mask, xb16);

    gemm_mfma<0><<<gg, 256, 0, stream>>>(xb16, WoT, bo, out);
}

// Round 3
// 305.995 us; speedup vs baseline: 5.3375x; 1.0016x over previous
//
#include <hip/hip_runtime.h>

#define SEQ    2048
#define DMODEL 512
#define NHEAD  8
#define HDIM   64
#define BATCH  4

#define LOG2E  1.4426950408889634f
#define QSCALE 0.18033688011112042f   // 0.125 * log2(e)
#define M0F    24.0f                  // fixed softmax max (scores*log2e << 24)

typedef short s16x8 __attribute__((ext_vector_type(8)));
typedef float f32x4 __attribute__((ext_vector_type(4)));
typedef float f32x16 __attribute__((ext_vector_type(16)));
typedef _Float16 f16x8 __attribute__((ext_vector_type(8)));

union U4S { uint4 u; s16x8 s; };

// fp32 -> bf16 RNE-ish (single value)
static __device__ inline unsigned short f2bf(float x) {
    unsigned int u = __builtin_bit_cast(unsigned int, x);
    u += 0x7fffu + ((u >> 16) & 1u);
    return (unsigned short)(u >> 16);
}

// pack two fp32 -> two bf16 in one u32 (round half-away via +0x8000, then
// v_perm_b32 grabs the two high halves). lo in bits 0..15, hi in 16..31.
static __device__ inline unsigned int pk2(float lo, float hi) {
    unsigned int a = __builtin_bit_cast(unsigned int, lo) + 0x8000u;
    unsigned int b = __builtin_bit_cast(unsigned int, hi) + 0x8000u;
    return __builtin_amdgcn_perm(b, a, 0x07060302u);
}

// async 16B/lane global->LDS copy (lds base must be wave-uniform)
static __device__ inline void async_cp16(const void* g, void* l) {
    __builtin_amdgcn_global_load_lds(
        (const __attribute__((address_space(1))) unsigned int*)g,
        (__attribute__((address_space(3))) unsigned int*)l,
        16, 0, 0);
}

// ---------------------------------------------------------------------------
// Transpose-cast the four 512x512 weight matrices: W[k][n] -> Wt[n][k] bf16
// ---------------------------------------------------------------------------
__global__ __launch_bounds__(256) void transpose_cast_w(
    const float* __restrict__ s0, const float* __restrict__ s1,
    const float* __restrict__ s2, const float* __restrict__ s3,
    unsigned short* __restrict__ d0, unsigned short* __restrict__ d1,
    unsigned short* __restrict__ d2, unsigned short* __restrict__ d3)
{
    const float* S; unsigned short* D;
    switch (blockIdx.z) {
        case 0: S = s0; D = d0; break;
        case 1: S = s1; D = d1; break;
        case 2: S = s2; D = d2; break;
        default: S = s3; D = d3; break;
    }
    __shared__ float T[32][33];
    const int t = threadIdx.x;
    const int r = t >> 3, c = (t & 7) * 4;
    const int k0 = blockIdx.x * 32, n0 = blockIdx.y * 32;
    float4 v = *(const float4*)&S[(size_t)(k0 + r) * DMODEL + n0 + c];
    T[r][c] = v.x; T[r][c + 1] = v.y; T[r][c + 2] = v.z; T[r][c + 3] = v.w;
    __syncthreads();
    ushort4 o;
    o.x = f2bf(T[c + 0][r]); o.y = f2bf(T[c + 1][r]);
    o.z = f2bf(T[c + 2][r]); o.w = f2bf(T[c + 3][r]);
    *(ushort4*)&D[(size_t)(n0 + r) * DMODEL + k0 + c] = o;
}

// ---------------------------------------------------------------------------
// Mask pre-pass: maskp = fp16(mask * log2e), permuted so an attention lane's
// values are contiguous.  Element (q,k): kt=k>>6, kl=k&63 decomposed as
// kl = 32*mt + 8*g + 4*hl + r  ->  out[((kt*SEQ+q)*64) + hl*32 + mt*16 + g*4 + r]
// ---------------------------------------------------------------------------
__global__ __launch_bounds__(256) void prep_mask(
    const float* __restrict__ mask, unsigned short* __restrict__ mp)
{
    int i = blockIdx.x * 256 + threadIdx.x;     // float4 index
    int k = (i * 4) & (SEQ - 1);
    int q = (i * 4) >> 11;
    float4 v = ((const float4*)mask)[i];
    int kt = k >> 6, kl = k & 63;
    int mt = kl >> 5, g = (kl >> 3) & 3, hl = (kl >> 2) & 1;
    size_t base = ((size_t)kt * SEQ + q) * 64 + hl * 32 + mt * 16 + g * 4;
    _Float16 h0 = (_Float16)(v.x * LOG2E);
    _Float16 h1 = (_Float16)(v.y * LOG2E);
    _Float16 h2 = (_Float16)(v.z * LOG2E);
    _Float16 h3 = (_Float16)(v.w * LOG2E);
    ushort4 o;
    o.x = __builtin_bit_cast(unsigned short, h0);
    o.y = __builtin_bit_cast(unsigned short, h1);
    o.z = __builtin_bit_cast(unsigned short, h2);
    o.w = __builtin_bit_cast(unsigned short, h3);
    *(ushort4*)&mp[base] = o;
}

// ---------------------------------------------------------------------------
// Per-head transpose of the V projection: vb[b*SEQ+key][h*64+dv] ->
// vT[((b*8+h)*64+dv)*SEQ + key]
// ---------------------------------------------------------------------------
__global__ __launch_bounds__(256) void transpose_v(
    const unsigned short* __restrict__ vb, unsigned short* __restrict__ vT)
{
    const int t = threadIdx.x;
    const int key0 = blockIdx.x * 64;
    const int bh = blockIdx.y, b = bh >> 3, h = bh & 7;
    #pragma unroll
    for (int p = 0; p < 2; p++) {
        int cid = p * 256 + t;
        int dv = cid >> 3, kch = cid & 7;
        unsigned short tmp[8];
        #pragma unroll
        for (int j = 0; j < 8; j++)
            tmp[j] = vb[(size_t)(b * SEQ + key0 + kch * 8 + j) * DMODEL + h * HDIM + dv];
        uint4 o;
        o.x = tmp[0] | ((unsigned)tmp[1] << 16);
        o.y = tmp[2] | ((unsigned)tmp[3] << 16);
        o.z = tmp[4] | ((unsigned)tmp[5] << 16);
        o.w = tmp[6] | ((unsigned)tmp[7] << 16);
        *(uint4*)&vT[(size_t)((b * NHEAD + h) * HDIM + dv) * SEQ + key0 + kch * 8] = o;
    }
}

// ---------------------------------------------------------------------------
// GEMM: C[8192][512] = A[8192][512] @ Bt[512][512]^T + bias, then * oscale.
// A_FP32: A is fp32, cast fused into LDS staging (register path).
// else:   A is bf16, staged with async global_load_lds (m97 path).
// 128x64 tile, BK=32, 4 waves, wave = 64m x 32n of 16x16x32 MFMA.
// ---------------------------------------------------------------------------
template <int A_FP32, int WRITE_BF16>
__global__ __launch_bounds__(256) void gemm2(
    const void* __restrict__ Ap, const unsigned short* __restrict__ Bt,
    const float* __restrict__ bias, void* __restrict__ Cout, float oscale)
{
    __shared__ __align__(16) unsigned short As[128 * 32];
    __shared__ __align__(16) unsigned short Bs[64 * 32];

    const int t = threadIdx.x;
    const int lane = t & 63, w = t >> 6;
    const int wm = w >> 1, wn = w & 1;
    const int c = lane & 15, quad = lane >> 4;
    const int bm = blockIdx.y * 128, bn = blockIdx.x * 64;

    f32x4 acc[4][2] = {};

    for (int k0 = 0; k0 < DMODEL; k0 += 32) {
        if (A_FP32) {
            const float* Af = (const float*)Ap;
            #pragma unroll
            for (int p = 0; p < 2; p++) {
                int cid = p * 256 + t;
                int row = cid >> 2, fc = cid & 3;
                const float* gp = &Af[(size_t)(bm + row) * DMODEL + k0 + fc * 8];
                float4 a0 = *(const float4*)gp;
                float4 a1 = *(const float4*)(gp + 4);
                uint4 pkd;
                pkd.x = pk2(a0.x, a0.y); pkd.y = pk2(a0.z, a0.w);
                pkd.z = pk2(a1.x, a1.y); pkd.w = pk2(a1.z, a1.w);
                *(uint4*)&As[row * 32 + fc * 8] = pkd;
            }
        } else {
            const unsigned short* Ab = (const unsigned short*)Ap;
            #pragma unroll
            for (int i = 0; i < 2; i++) {
                int row = 32 * w + 16 * i + (lane >> 2);
                const unsigned short* gp = Ab + (size_t)(bm + row) * DMODEL + k0 + (lane & 3) * 8;
                async_cp16(gp, &As[w * 1024 + i * 512]);
            }
        }
        {
            int row = 16 * w + (lane >> 2);
            const unsigned short* gp = Bt + (size_t)(bn + row) * DMODEL + k0 + (lane & 3) * 8;
            async_cp16(gp, &Bs[w * 512]);
        }
        __syncthreads();

        s16x8 af[4], bfr[2];
        #pragma unroll
        for (int mt = 0; mt < 4; mt++)
            af[mt] = *(const s16x8*)&As[(wm * 64 + mt * 16 + c) * 32 + quad * 8];
        #pragma unroll
        for (int nt = 0; nt < 2; nt++)
            bfr[nt] = *(const s16x8*)&Bs[(wn * 32 + nt * 16 + c) * 32 + quad * 8];
        #pragma unroll
        for (int mt = 0; mt < 4; mt++)
            #pragma unroll
            for (int nt = 0; nt < 2; nt++)
                acc[mt][nt] = __builtin_amdgcn_mfma_f32_16x16x32_bf16(
                    af[mt], bfr[nt], acc[mt][nt], 0, 0, 0);
        __syncthreads();
    }

    #pragma unroll
    for (int nt = 0; nt < 2; nt++) {
        int ng = bn + wn * 32 + nt * 16 + c;
        float bv = bias[ng];
        #pragma unroll
        for (int mt = 0; mt < 4; mt++) {
            #pragma unroll
            for (int r = 0; r < 4; r++) {
                int mg = bm + wm * 64 + mt * 16 + quad * 4 + r;
                float v = (acc[mt][nt][r] + bv) * oscale;
                if (WRITE_BF16)
                    ((unsigned short*)Cout)[(size_t)mg * DMODEL + ng] = f2bf(v);
                else
                    ((float*)Cout)[(size_t)mg * DMODEL + ng] = v;
            }
        }
    }
}

// ---------------------------------------------------------------------------
// Flash attention, 32x32x16 MFMA, S^T trick, fixed-max softmax.
// Block = (b,head) x 128 q rows; 4 waves, wave w owns q = q0+32w+(lane&31).
// S^T = K.Q^T  (A=K[m=key], B=Q[n=q]) -> lane holds 1 q x 16 keys.
// P stays in registers: a 4x shfl_xor(32) block swap converts C-layout to the
// PV B-operand layout.  O^T accumulated per wave (no cross-wave reduction).
// LDS tiles chunk-major: Ks[featchunk][key][8], Vs[keychunk][dv][8].
// ---------------------------------------------------------------------------
__global__ __launch_bounds__(256) void attn2(
    const unsigned short* __restrict__ qb, const unsigned short* __restrict__ kb,
    const unsigned short* __restrict__ vT, const unsigned short* __restrict__ maskp,
    unsigned short* __restrict__ X)
{
    __shared__ __align__(16) unsigned short Ks[8][64][8];
    __shared__ __align__(16) unsigned short Vs[8][64][8];

    const int t = threadIdx.x;
    const int lane = t & 63, w = t >> 6;
    const int c32 = lane & 31, hl = lane >> 5;
    const int bh = blockIdx.x, b = bh >> 3, head = bh & 7;
    const int q0 = blockIdx.y * 128;
    const int qg = q0 + w * 32 + c32;

    // hoisted Q B-frags (read once from global; q pre-scaled by 0.125*log2e)
    const unsigned short* qrow = qb + ((size_t)b * SEQ + qg) * DMODEL + head * HDIM;
    s16x8 Qf[4];
    #pragma unroll
    for (int s = 0; s < 4; s++)
        Qf[s] = *(const s16x8*)&qrow[s * 16 + hl * 8];

    const unsigned short* kgb = kb + (size_t)b * SEQ * DMODEL + head * HDIM;
    const unsigned short* vgb = vT + (size_t)bh * HDIM * SEQ;

    f32x16 O0 = {}, O1 = {};   // O^T partial: dv rows (0..31 / 32..63), col = own q
    float lsum = 0.f;

    for (int kt = 0; kt < SEQ / 64; kt++) {
        const int k0 = kt * 64;
        // ---- stage K and V^T, chunk-major ----
        #pragma unroll
        for (int p = 0; p < 2; p++) {
            int cid = p * 256 + t;
            int r8 = cid >> 3, ch = cid & 7;
            uint4 kv = *(const uint4*)&kgb[(size_t)(k0 + r8) * DMODEL + ch * 8];
            *(uint4*)&Ks[ch][r8][0] = kv;
            uint4 vv = *(const uint4*)&vgb[(size_t)r8 * SEQ + k0 + ch * 8];
            *(uint4*)&Vs[ch][r8][0] = vv;
        }
        __syncthreads();

        // ---- S^T = K.Q^T : 2 key-tiles x 4 feature-steps ----
        f32x16 S0 = {}, S1 = {};
        #pragma unroll
        for (int s = 0; s < 4; s++) {
            int fc = 2 * s + hl;
            s16x8 ka0 = *(const s16x8*)&Ks[fc][c32][0];
            s16x8 ka1 = *(const s16x8*)&Ks[fc][32 + c32][0];
            S0 = __builtin_amdgcn_mfma_f32_32x32x16_bf16(ka0, Qf[s], S0, 0, 0, 0);
            S1 = __builtin_amdgcn_mfma_f32_32x32x16_bf16(ka1, Qf[s], S1, 0, 0, 0);
        }

        // ---- softmax (fixed max) + bf16 pack + half-wave block exchange ----
        unsigned int Pf[4][4];
        const unsigned short* mrow = maskp + ((size_t)kt * SEQ + qg) * 64 + hl * 32;
        #pragma unroll
        for (int mt = 0; mt < 2; mt++) {
            f32x16 S = mt ? S1 : S0;
            f16x8 mh0 = *(const f16x8*)&mrow[mt * 16];
            f16x8 mh1 = *(const f16x8*)&mrow[mt * 16 + 8];
            float p[16];
            #pragma unroll
            for (int j = 0; j < 8; j++) {
                p[j]     = __builtin_amdgcn_exp2f(S[j]     + (float)mh0[j] - M0F);
                p[8 + j] = __builtin_amdgcn_exp2f(S[8 + j] + (float)mh1[j] - M0F);
            }
            #pragma unroll
            for (int j = 0; j < 16; j++) lsum += p[j];
            unsigned int u[4][2];
            #pragma unroll
            for (int g = 0; g < 4; g++) {
                u[g][0] = pk2(p[g * 4 + 0], p[g * 4 + 1]);
                u[g][1] = pk2(p[g * 4 + 2], p[g * 4 + 3]);
            }
            // exchange blocks between lane-halves (hl=0 sends g1,g3; hl=1 sends g0,g2)
            unsigned int sA0 = hl ? u[0][0] : u[1][0];
            unsigned int sA1 = hl ? u[0][1] : u[1][1];
            unsigned int sB0 = hl ? u[2][0] : u[3][0];
            unsigned int sB1 = hl ? u[2][1] : u[3][1];
            unsigned int rA0 = (unsigned)__shfl_xor((int)sA0, 32, 64);
            unsigned int rA1 = (unsigned)__shfl_xor((int)sA1, 32, 64);
            unsigned int rB0 = (unsigned)__shfl_xor((int)sB0, 32, 64);
            unsigned int rB1 = (unsigned)__shfl_xor((int)sB1, 32, 64);
            Pf[2 * mt + 0][0] = hl ? rA0 : u[0][0];
            Pf[2 * mt + 0][1] = hl ? rA1 : u[0][1];
            Pf[2 * mt + 0][2] = hl ? u[1][0] : rA0;
            Pf[2 * mt + 0][3] = hl ? u[1][1] : rA1;
            Pf[2 * mt + 1][0] = hl ? rB0 : u[2][0];
            Pf[2 * mt + 1][1] = hl ? rB1 : u[2][1];
            Pf[2 * mt + 1][2] = hl ? u[3][0] : rB0;
            Pf[2 * mt + 1][3] = hl ? u[3][1] : rB1;
        }

        // ---- O^T += V^T . P : 2 dv-tiles x 4 key-steps ----
        #pragma unroll
        for (int s = 0; s < 4; s++) {
            int kc = 2 * s + hl;
            s16x8 va0 = *(const s16x8*)&Vs[kc][c32][0];
            s16x8 va1 = *(const s16x8*)&Vs[kc][32 + c32][0];
            U4S pu; pu.u = make_uint4(Pf[s][0], Pf[s][1], Pf[s][2], Pf[s][3]);
            O0 = __builtin_amdgcn_mfma_f32_32x32x16_bf16(va0, pu.s, O0, 0, 0, 0);
            O1 = __builtin_amdgcn_mfma_f32_32x32x16_bf16(va1, pu.s, O1, 0, 0, 0);
        }
        __syncthreads();
    }

    // ---- epilogue: combine lane-halves' l, scale, store bf16 ----
    lsum += __shfl_xor(lsum, 32, 64);
    float inv = 1.0f / lsum;
    unsigned short* xrow = X + (((size_t)head * SEQ + qg) * BATCH + b) * HDIM;
    #pragma unroll
    for (int mt = 0; mt < 2; mt++) {
        f32x16 Ov = mt ? O1 : O0;
        #pragma unroll
        for (int g = 0; g < 4; g++) {
            unsigned int lo = pk2(Ov[g * 4 + 0] * inv, Ov[g * 4 + 1] * inv);
            unsigned int hi = pk2(Ov[g * 4 + 2] * inv, Ov[g * 4 + 3] * inv);
            uint2 st = make_uint2(lo, hi);
            *(uint2*)&xrow[mt * 32 + 8 * g + 4 * hl] = st;
        }
    }
}

// ---------------------------------------------------------------------------
extern "C" void kernel_launch(void* const* d_in, const int* in_sizes, int n_in,
                              void* d_out, int out_size, void* d_ws, size_t ws_size,
                              hipStream_t stream) {
    const float* query = (const float*)d_in[0];
    const float* key_  = (const float*)d_in[1];
    const float* value = (const float*)d_in[2];
    const float* mask  = (const float*)d_in[3];
    const float* Wq = (const float*)d_in[4];
    const float* bq = (const float*)d_in[5];
    const float* Wk = (const float*)d_in[6];
    const float* bk = (const float*)d_in[7];
    const float* Wv = (const float*)d_in[8];
    const float* bv = (const float*)d_in[9];
    const float* Wo = (const float*)d_in[10];
    const float* bo = (const float*)d_in[11];
    float* out = (float*)d_out;

    const size_t NP = (size_t)BATCH * SEQ * DMODEL;   // 4194304
    unsigned short* ws   = (unsigned short*)d_ws;
    unsigned short* qb16 = ws;
    unsigned short* kb16 = qb16 + NP;
    unsigned short* vb16 = kb16 + NP;
    unsigned short* vT16 = vb16 + NP;
    unsigned short* xb16 = vT16 + NP;
    unsigned short* mp16 = xb16 + NP;                 // SEQ*SEQ fp16 = 4M elems
    unsigned short* WqT  = mp16 + (size_t)SEQ * SEQ;
    unsigned short* WkT  = WqT + DMODEL * DMODEL;
    unsigned short* WvT  = WkT + DMODEL * DMODEL;
    unsigned short* WoT  = WvT + DMODEL * DMODEL;
    // total: 6*8MB + 4*0.5MB = 50MB

    transpose_cast_w<<<dim3(16, 16, 4), 256, 0, stream>>>(
        Wq, Wk, Wv, Wo, WqT, WkT, WvT, WoT);
    prep_mask<<<dim3(SEQ * SEQ / 4 / 256), 256, 0, stream>>>(mask, mp16);

    dim3 gg(DMODEL / 64, BATCH * SEQ / 128);   // (8, 64)
    gemm2<1, 1><<<gg, 256, 0, stream>>>(query, WqT, bq, qb16, QSCALE);
    gemm2<1, 1><<<gg, 256, 0, stream>>>(key_,  WkT, bk, kb16, 1.0f);
    gemm2<1, 1><<<gg, 256, 0, stream>>>(value, WvT, bv, vb16, 1.0f);

    transpose_v<<<dim3(SEQ / 64, BATCH * NHEAD), 256, 0, stream>>>(vb16, vT16);

    attn2<<<dim3(BATCH * NHEAD, SEQ / 128), 256, 0, stream>>>(
        qb16, kb16, vT16, mp16, xb16);

    gemm2<0, 0><<<gg, 256, 0, stream>>>(xb16, WoT, bo, out, 1.0f);
}